// Round 4
// baseline (257.396 us; speedup 1.0000x reference)
//
#include <hip/hip_runtime.h>
#include <cstdint>
#include <cstddef>

#define NNODES 100000
#define FEATD  256
#define HIDD   256
#define NBATCH 512
#define FAN1   10            // hop-1 fanout
#define FAN2   25            // hop-2 fanout
#define NS1    (NBATCH*FAN1) // 5120
#define MTOT   (NBATCH+NS1)  // 5632
#define NBLK   (MTOT/16)     // 352
#define NHOP   (NS1/16)      // 320 hop-producer blocks (ids 0..319)
#define CBASE  NHOP          // consumer/batch blocks: ids 320..351

typedef __attribute__((ext_vector_type(8))) short short8;
typedef __attribute__((ext_vector_type(4))) float f32x4;

__device__ __forceinline__ unsigned short f2bf(float f) {
    unsigned int u = __float_as_uint(f);
    unsigned int r = (u + 0x7fffu + ((u >> 16) & 1u)) >> 16;
    return (unsigned short)r;
}
__device__ __forceinline__ float bf2f(unsigned short h) {
    return __uint_as_float(((unsigned int)h) << 16);
}

__device__ __forceinline__ void wait_flag(int* p, int target) {
    // device-scope acquire spin on one thread; rest of block parks at the
    // following __syncthreads(). Waits ONLY on lower-block-id producers =>
    // deadlock-free even without full co-residency.
    while (__hip_atomic_load(p, __ATOMIC_ACQUIRE, __HIP_MEMORY_SCOPE_AGENT) < target)
        __builtin_amdgcn_s_sleep(2);
}

// tiny pre-kernel: zero the 33 flag words (workspace is poison-filled between
// replays). Same-stream serialization makes the zeros visible to k_fused.
__global__ void k_zero(int* __restrict__ f) {
    if (threadIdx.x < 33) f[threadIdx.x] = 0;
}

// ================= fused kernel: wcvt + gather/mean/GEMM0 + GEMM1/norm ==========
// 352 blocks x 256 threads (4 waves). DEADLOCK-SAFE ORDERING: all spin-waits
// point at LOWER block ids (HW dispatches in id order, earlier blocks always
// complete), so correctness never depends on co-residency.
//   blocks 0..63   : convert/transpose one 64x64 W tile each -> B0t/B1t, ++flags[0]
//   blocks 0..319  : gather hop-2 rows (fan-25) + mean -> layer-0 GEMM -> H1,
//                    then ++flags[1 + bid/10] and exit
//   blocks 320..351: gather batch rows (fan-10) + mean -> layer-0 GEMM -> H0,
//                    wait flags[1+g]==10 (their 10 producers, all earlier ids),
//                    then layer-1 GEMM + H1-mean + row L2-norm -> out
__global__ __launch_bounds__(256, 3) void k_fused(
    const float* __restrict__ feat, const int* __restrict__ adj,
    const int* __restrict__ batch,
    const float* __restrict__ Ws0, const float* __restrict__ Wn0,
    const float* __restrict__ Ws1, const float* __restrict__ Wn1,
    unsigned short* __restrict__ B0t, unsigned short* __restrict__ B1t,
    unsigned short* __restrict__ H0, unsigned short* __restrict__ H1,
    int* __restrict__ flags, float* __restrict__ out) {
    __shared__ unsigned short Ts[64][72];                  // wcvt transpose tile
    __shared__ __align__(16) unsigned short As[16][520];   // A-panel (l0 and l1)
    __shared__ float rn[16][4];                            // l1 cross-wave norm
    const int t   = threadIdx.x;
    const int bid = blockIdx.x;
    const int wv  = t >> 6;      // 0..3
    const int l   = t & 63;
    const int q   = l >> 4;
    const int m15 = l & 15;
    const bool isHop = (bid < NHOP);

    // ---- Phase W: weight convert+transpose, blocks 0..63 (one 64x64 tile each) ----
    if (bid < 64) {
        const int which = bid >> 5;
        const int loc   = bid & 31;
        const int kt = loc >> 2, nt = loc & 3;
        const int k0 = kt * 64, n0 = nt * 64;
        const float* W;
        if (which == 0)
            W = (k0 < 256) ? (Ws0 + (size_t)k0 * 256) : (Wn0 + (size_t)(k0 - 256) * 256);
        else
            W = (k0 < 256) ? (Ws1 + (size_t)k0 * 256) : (Wn1 + (size_t)(k0 - 256) * 256);
        unsigned short* Bt = which ? B1t : B0t;
        #pragma unroll
        for (int i = 0; i < 4; ++i) {
            int s  = t + i * 256;
            int kr = s >> 4;
            int c4 = s & 15;
            float4 v = *reinterpret_cast<const float4*>(W + (size_t)kr * 256 + n0 + c4 * 4);
            Ts[c4 * 4 + 0][kr] = f2bf(v.x);
            Ts[c4 * 4 + 1][kr] = f2bf(v.y);
            Ts[c4 * 4 + 2][kr] = f2bf(v.z);
            Ts[c4 * 4 + 3][kr] = f2bf(v.w);
        }
        __syncthreads();
        #pragma unroll
        for (int i = 0; i < 2; ++i) {
            int s  = t + i * 256;
            int nl = s >> 3;
            int k8 = (s & 7) * 8;
            *reinterpret_cast<short8*>(Bt + (size_t)(n0 + nl) * 512 + k0 + k8) =
                *reinterpret_cast<const short8*>(&Ts[nl][k8]);
        }
        __threadfence();        // order this thread's B*t stores device-wide
        __syncthreads();
        if (t == 0)
            __hip_atomic_fetch_add(&flags[0], 1, __ATOMIC_RELEASE, __HIP_MEMORY_SCOPE_AGENT);
    }

    // ---- Phase G: gather 4 rows per wave + neighbor mean -> As ----
    // hop block b: H1 rows b*16..b*16+15 (fan-25). consumer block: batch rows
    // (b-320)*16.. (fan-10).
    const int rbase = isHop ? bid * 16 : (bid - CBASE) * 16;
    #pragma unroll
    for (int i = 0; i < 4; ++i) {
        const int r   = wv * 4 + i;
        const int idx = rbase + r;
        int node;
        if (isHop) {
            int b = idx / FAN1;
            int j = idx - b * FAN1;
            node  = adj[(size_t)batch[b] * FAN2 + j];
        } else {
            node = batch[idx];
        }
        float4 selfv = *reinterpret_cast<const float4*>(
            feat + (size_t)node * FEATD + l * 4);
        const int* arow = adj + (size_t)node * FAN2;
        int myidx = (l < FAN2) ? arow[l] : 0;
        float4 acc = make_float4(0.f, 0.f, 0.f, 0.f);
        float s;
        if (isHop) {
            #pragma unroll
            for (int k = 0; k < FAN2; ++k) {
                int nb = __shfl(myidx, k);
                float4 v = *reinterpret_cast<const float4*>(
                    feat + (size_t)nb * FEATD + l * 4);
                acc.x += v.x; acc.y += v.y; acc.z += v.z; acc.w += v.w;
            }
            s = 1.0f / (float)FAN2;
        } else {
            #pragma unroll
            for (int k = 0; k < FAN1; ++k) {
                int nb = __shfl(myidx, k);
                float4 v = *reinterpret_cast<const float4*>(
                    feat + (size_t)nb * FEATD + l * 4);
                acc.x += v.x; acc.y += v.y; acc.z += v.z; acc.w += v.w;
            }
            s = 1.0f / (float)FAN1;
        }
        acc.x *= s; acc.y *= s; acc.z *= s; acc.w *= s;
        ushort4 ps, pn;
        ps.x = f2bf(selfv.x); ps.y = f2bf(selfv.y);
        ps.z = f2bf(selfv.z); ps.w = f2bf(selfv.w);
        pn.x = f2bf(acc.x);   pn.y = f2bf(acc.y);
        pn.z = f2bf(acc.z);   pn.w = f2bf(acc.w);
        *reinterpret_cast<ushort4*>(&As[r][l * 4])       = ps;
        *reinterpret_cast<ushort4*>(&As[r][256 + l * 4]) = pn;
    }
    __syncthreads();

    // ---- wait for all 64 W tiles (blocks 0..63, all earlier/equal ids; the
    // fan-25 gather above is far longer than one wcvt tile, so this is free) ----
    if (t == 0) wait_flag(&flags[0], 64);
    __syncthreads();

    // ---- Phase B: layer-0 barrier-free MFMA K-loop, B0t from global (L2) ----
    {
        f32x4 acc0 = (f32x4)0.f, acc1 = (f32x4)0.f, acc2 = (f32x4)0.f, acc3 = (f32x4)0.f;
        const unsigned short* b0p = B0t + (size_t)(wv * 64 +  0 + m15) * 512;
        const unsigned short* b1p = B0t + (size_t)(wv * 64 + 16 + m15) * 512;
        const unsigned short* b2p = B0t + (size_t)(wv * 64 + 32 + m15) * 512;
        const unsigned short* b3p = B0t + (size_t)(wv * 64 + 48 + m15) * 512;
        #pragma unroll
        for (int kt = 0; kt < 16; ++kt) {
            const int kk = kt * 32 + q * 8;
            short8 a  = *reinterpret_cast<const short8*>(&As[m15][kk]);
            short8 b0 = *reinterpret_cast<const short8*>(b0p + kk);
            short8 b1 = *reinterpret_cast<const short8*>(b1p + kk);
            short8 b2 = *reinterpret_cast<const short8*>(b2p + kk);
            short8 b3 = *reinterpret_cast<const short8*>(b3p + kk);
            acc0 = __builtin_amdgcn_mfma_f32_16x16x32_bf16(a, b0, acc0, 0, 0, 0);
            acc1 = __builtin_amdgcn_mfma_f32_16x16x32_bf16(a, b1, acc1, 0, 0, 0);
            acc2 = __builtin_amdgcn_mfma_f32_16x16x32_bf16(a, b2, acc2, 0, 0, 0);
            acc3 = __builtin_amdgcn_mfma_f32_16x16x32_bf16(a, b3, acc3, 0, 0, 0);
        }
        // epilogue: relu + bf16 write. hop -> H1 (flagged), consumer -> H0 (self-consumed)
        #pragma unroll
        for (int f = 0; f < 4; ++f) {
            const int n = wv * 64 + f * 16 + m15;
            const f32x4& a = (f == 0) ? acc0 : (f == 1) ? acc1 : (f == 2) ? acc2 : acc3;
            #pragma unroll
            for (int j = 0; j < 4; ++j) {
                int m = rbase + q * 4 + j;
                unsigned short v = f2bf(fmaxf(a[j], 0.f));
                if (isHop)
                    H1[(size_t)m * HIDD + n] = v;
                else
                    H0[(size_t)m * HIDD + n] = v;
            }
        }
    }
    __threadfence();            // order H0/H1 stores device-wide (per thread)
    __syncthreads();

    if (isHop) {
        // hop block b produced H1 rows b*16..b*16+15, wholly inside group b/10
        if (t == 0)
            __hip_atomic_fetch_add(&flags[1 + bid / 10], 1,
                                   __ATOMIC_RELEASE, __HIP_MEMORY_SCOPE_AGENT);
        return;
    }

    // ---- Phase C (blocks 320..351): layer-1 GEMM + H1-mean + L2 norm ----
    // group g = bid-320 needs H1 rows g*160..g*160+159 = producers 10g..10g+9
    // (all earlier block ids -> safe wait).
    const int g  = bid - CBASE;
    const int rb = rbase;       // == g*16
    if (t == 0) wait_flag(&flags[1 + g], 10);
    __syncthreads();

    // stage H0 half (written by this very block, L2/L1-hot): 512 slots, 2/thread
    #pragma unroll
    for (int i = 0; i < 2; ++i) {
        int s = t + i * 256;
        int r = s >> 5, c8 = (s & 31) * 8;
        *reinterpret_cast<short8*>(&As[r][c8]) =
            *reinterpret_cast<const short8*>(H0 + (size_t)(rb + r) * HIDD + c8);
    }
    // stage mean(H1) half: 512 slots, 2/thread, each averages 10 bf16 rows in fp32
    #pragma unroll
    for (int i = 0; i < 2; ++i) {
        int s = t + i * 256;
        int r = s >> 5, c8 = (s & 31) * 8;
        const unsigned short* base = H1 + (size_t)(rb + r) * FAN1 * HIDD + c8;
        float a[8];
        #pragma unroll
        for (int e = 0; e < 8; ++e) a[e] = 0.f;
        #pragma unroll
        for (int j = 0; j < FAN1; ++j) {
            short8 v = *reinterpret_cast<const short8*>(base + (size_t)j * HIDD);
            #pragma unroll
            for (int e = 0; e < 8; ++e) a[e] += bf2f((unsigned short)v[e]);
        }
        short8 p;
        #pragma unroll
        for (int e = 0; e < 8; ++e) p[e] = (short)f2bf(a[e] * (1.0f / FAN1));
        *reinterpret_cast<short8*>(&As[r][256 + c8]) = p;
    }
    __syncthreads();

    f32x4 acc0 = (f32x4)0.f, acc1 = (f32x4)0.f, acc2 = (f32x4)0.f, acc3 = (f32x4)0.f;
    const unsigned short* b0p = B1t + (size_t)(wv * 64 +  0 + m15) * 512;
    const unsigned short* b1p = B1t + (size_t)(wv * 64 + 16 + m15) * 512;
    const unsigned short* b2p = B1t + (size_t)(wv * 64 + 32 + m15) * 512;
    const unsigned short* b3p = B1t + (size_t)(wv * 64 + 48 + m15) * 512;
    #pragma unroll
    for (int kt = 0; kt < 16; ++kt) {
        const int kk = kt * 32 + q * 8;
        short8 a  = *reinterpret_cast<const short8*>(&As[m15][kk]);
        short8 b0 = *reinterpret_cast<const short8*>(b0p + kk);
        short8 b1 = *reinterpret_cast<const short8*>(b1p + kk);
        short8 b2 = *reinterpret_cast<const short8*>(b2p + kk);
        short8 b3 = *reinterpret_cast<const short8*>(b3p + kk);
        acc0 = __builtin_amdgcn_mfma_f32_16x16x32_bf16(a, b0, acc0, 0, 0, 0);
        acc1 = __builtin_amdgcn_mfma_f32_16x16x32_bf16(a, b1, acc1, 0, 0, 0);
        acc2 = __builtin_amdgcn_mfma_f32_16x16x32_bf16(a, b2, acc2, 0, 0, 0);
        acc3 = __builtin_amdgcn_mfma_f32_16x16x32_bf16(a, b3, acc3, 0, 0, 0);
    }

    // per-row sum of squares: 16-lane shuffle within wave, then cross-wave via LDS
    #pragma unroll
    for (int j = 0; j < 4; ++j) {
        float p = acc0[j] * acc0[j] + acc1[j] * acc1[j]
                + acc2[j] * acc2[j] + acc3[j] * acc3[j];
        p += __shfl_xor(p, 1);
        p += __shfl_xor(p, 2);
        p += __shfl_xor(p, 4);
        p += __shfl_xor(p, 8);
        if (m15 == 0) rn[q * 4 + j][wv] = p;
    }
    __syncthreads();

    #pragma unroll
    for (int j = 0; j < 4; ++j) {
        const int m = q * 4 + j;
        float s = rn[m][0] + rn[m][1] + rn[m][2] + rn[m][3];
        float inv = 1.0f / fmaxf(sqrtf(s), 1e-12f);
        out[(size_t)(rb + m) * HIDD + wv * 64 +  0 + m15] = acc0[j] * inv;
        out[(size_t)(rb + m) * HIDD + wv * 64 + 16 + m15] = acc1[j] * inv;
        out[(size_t)(rb + m) * HIDD + wv * 64 + 32 + m15] = acc2[j] * inv;
        out[(size_t)(rb + m) * HIDD + wv * 64 + 48 + m15] = acc3[j] * inv;
    }
}

extern "C" void kernel_launch(void* const* d_in, const int* in_sizes, int n_in,
                              void* d_out, int out_size, void* d_ws, size_t ws_size,
                              hipStream_t stream) {
    const float* feat  = (const float*)d_in[0];
    const int*   adj   = (const int*)d_in[1];
    const int*   batch = (const int*)d_in[2];
    const float* Ws0   = (const float*)d_in[3];
    const float* Wn0   = (const float*)d_in[4];
    const float* Ws1   = (const float*)d_in[5];
    const float* Wn1   = (const float*)d_in[6];
    float* out = (float*)d_out;

    // ws: B0t bf16 @0 (262144); B1t @262144 (262144); H0 bf16 [512][256]
    // @524288 (262144); H1 bf16 [5120][256] @786432 (2621440);
    // flags (33 x int: flagW + 32 group counters) @3407872.
    char* ws = (char*)d_ws;
    unsigned short* B0t = (unsigned short*)(ws + 0);
    unsigned short* B1t = (unsigned short*)(ws + 262144);
    unsigned short* H0  = (unsigned short*)(ws + 524288);
    unsigned short* H1  = (unsigned short*)(ws + 786432);
    int*            flg = (int*)(ws + 3407872);

    k_zero<<<1, 64, 0, stream>>>(flg);   // re-zero flags per replay (ws is poisoned)
    k_fused<<<NBLK, 256, 0, stream>>>(feat, adj, batch, Ws0, Wn0, Ws1, Wn1,
                                      B0t, B1t, H0, H1, flg, out);
}

// Round 5
// 193.403 us; speedup vs baseline: 1.3309x; 1.3309x over previous
//
#include <hip/hip_runtime.h>
#include <cstdint>
#include <cstddef>

#define NNODES 100000
#define FEATD  256
#define HIDD   256
#define NBATCH 512
#define FAN1   10            // hop-1 fanout
#define FAN2   25            // hop-2 fanout
#define NS1    (NBATCH*FAN1) // 5120
#define MTOT   (NBATCH+NS1)  // 5632

typedef __attribute__((ext_vector_type(8))) short short8;
typedef __attribute__((ext_vector_type(4))) float f32x4;

__device__ __forceinline__ unsigned short f2bf(float f) {
    unsigned int u = __float_as_uint(f);
    unsigned int r = (u + 0x7fffu + ((u >> 16) & 1u)) >> 16;
    return (unsigned short)r;
}
__device__ __forceinline__ float bf2f(unsigned short h) {
    return __uint_as_float(((unsigned int)h) << 16);
}

// Neighbor-mean gather with EXPLICIT memory-level parallelism: 5-wide batches of
// named float4 temps, software-pipelined 2 deep (issue batch g+1 before
// consuming batch g) => ~10 KB in flight per wave. Round-4 counters showed the
// old per-k chain compiled to VGPR=68 (room for <5 in-flight loads) and ran
// latency-bound at 585 GB/s. All temp indices are compile-time (rule #20).
template<int FAN>
__device__ __forceinline__ float4 neigh_mean(
    const float* __restrict__ feat, const int* __restrict__ arow, int l) {
    static_assert(FAN % 5 == 0, "FAN must be a multiple of 5");
    int myidx = (l < FAN) ? arow[l] : 0;
    float4 c0, c1, c2, c3, c4, n0, n1, n2, n3, n4;
#define GLD(K) (*reinterpret_cast<const float4*>( \
        feat + (size_t)__shfl(myidx, (K)) * FEATD + l * 4))
    c0 = GLD(0); c1 = GLD(1); c2 = GLD(2); c3 = GLD(3); c4 = GLD(4);
    float4 a = make_float4(0.f, 0.f, 0.f, 0.f);
    constexpr int NB = FAN / 5;
    #pragma unroll
    for (int g = 0; g < NB; ++g) {
        if (g + 1 < NB) {   // issue next batch before consuming current
            n0 = GLD(5*g+5); n1 = GLD(5*g+6); n2 = GLD(5*g+7);
            n3 = GLD(5*g+8); n4 = GLD(5*g+9);
        }
        a.x += (c0.x + c1.x) + (c2.x + c3.x) + c4.x;
        a.y += (c0.y + c1.y) + (c2.y + c3.y) + c4.y;
        a.z += (c0.z + c1.z) + (c2.z + c3.z) + c4.z;
        a.w += (c0.w + c1.w) + (c2.w + c3.w) + c4.w;
        if (g + 1 < NB) { c0 = n0; c1 = n1; c2 = n2; c3 = n3; c4 = n4; }
    }
#undef GLD
    const float s = 1.0f / (float)FAN;
    a.x *= s; a.y *= s; a.z *= s; a.w *= s;
    return a;
}

// ---------------- kernel 1: W convert + transpose (both layers) ----------------
// B0t/B1t[n][k] bf16 (256 x 512): k<256 from Ws[k][n], k>=256 from Wn[k-256][n].
// 64 blocks: 0..31 -> layer 0, 32..63 -> layer 1.
__global__ __launch_bounds__(256) void k_wcvt(
    const float* __restrict__ Ws0, const float* __restrict__ Wn0,
    const float* __restrict__ Ws1, const float* __restrict__ Wn1,
    unsigned short* __restrict__ B0t, unsigned short* __restrict__ B1t) {
    __shared__ unsigned short Ts[64][72];
    const int t     = threadIdx.x;
    const int which = blockIdx.x >> 5;
    const int loc   = blockIdx.x & 31;
    const int kt = loc >> 2, nt = loc & 3;
    const int k0 = kt * 64, n0 = nt * 64;
    const float* W;
    if (which == 0)
        W = (k0 < 256) ? (Ws0 + (size_t)k0 * 256) : (Wn0 + (size_t)(k0 - 256) * 256);
    else
        W = (k0 < 256) ? (Ws1 + (size_t)k0 * 256) : (Wn1 + (size_t)(k0 - 256) * 256);
    unsigned short* Bt = which ? B1t : B0t;
    #pragma unroll
    for (int i = 0; i < 4; ++i) {
        int s  = t + i * 256;
        int kr = s >> 4;
        int c4 = s & 15;
        float4 v = *reinterpret_cast<const float4*>(W + (size_t)kr * 256 + n0 + c4 * 4);
        Ts[c4 * 4 + 0][kr] = f2bf(v.x);
        Ts[c4 * 4 + 1][kr] = f2bf(v.y);
        Ts[c4 * 4 + 2][kr] = f2bf(v.z);
        Ts[c4 * 4 + 3][kr] = f2bf(v.w);
    }
    __syncthreads();
    #pragma unroll
    for (int i = 0; i < 2; ++i) {
        int s  = t + i * 256;
        int nl = s >> 3;
        int k8 = (s & 7) * 8;
        *reinterpret_cast<short8*>(Bt + (size_t)(n0 + nl) * 512 + k0 + k8) =
            *reinterpret_cast<const short8*>(&Ts[nl][k8]);
    }
}

// ---------------- kernel 2: fused gather + neighbor-mean + bf16 MFMA GEMM ----------------
// 256 threads = 4 waves; block owns 16 rows x 256 cols. Each wave gathers 4 rows
// with the batched-MLP neigh_mean. GEMM: barrier-free K-loop, A frags from LDS,
// B frags straight from B0t (L2-resident). No min-waves pressure in
// launch_bounds: the allocator must keep ~10 float4 loads live (VGPR ~100+).
__global__ __launch_bounds__(256) void k_gg0(
    const float* __restrict__ feat, const int* __restrict__ adj,
    const int* __restrict__ batch, const unsigned short* __restrict__ B0t,
    unsigned short* __restrict__ H0, unsigned short* __restrict__ H1) {
    __shared__ __align__(16) unsigned short As[16][520];
    const int t   = threadIdx.x;
    const int wv  = t >> 6;      // 0..3
    const int l   = t & 63;
    const int q   = l >> 4;
    const int m15 = l & 15;
    const int r0  = blockIdx.x * 16;
    const bool isBatch = (r0 < NBATCH);

    // ---- Phase 1: gather 4 rows per wave, batched-MLP loads ----
    #pragma unroll
    for (int i = 0; i < 4; ++i) {
        const int r = wv * 4 + i;
        const int R = r0 + r;
        int node;
        if (isBatch) {
            node = batch[R];
        } else {
            int idx = R - NBATCH;
            int b   = idx / FAN1;
            int j   = idx - b * FAN1;
            node = adj[(size_t)batch[b] * FAN2 + j];
        }
        // self row issued first (FIFO => completes first, consumed last)
        float4 selfv = *reinterpret_cast<const float4*>(
            feat + (size_t)node * FEATD + l * 4);
        const int* arow = adj + (size_t)node * FAN2;
        float4 mean = isBatch ? neigh_mean<FAN1>(feat, arow, l)
                              : neigh_mean<FAN2>(feat, arow, l);
        ushort4 ps, pn;
        ps.x = f2bf(selfv.x); ps.y = f2bf(selfv.y);
        ps.z = f2bf(selfv.z); ps.w = f2bf(selfv.w);
        pn.x = f2bf(mean.x);  pn.y = f2bf(mean.y);
        pn.z = f2bf(mean.z);  pn.w = f2bf(mean.w);
        *reinterpret_cast<ushort4*>(&As[r][l * 4])       = ps;
        *reinterpret_cast<ushort4*>(&As[r][256 + l * 4]) = pn;
    }
    __syncthreads();

    // ---- Phase 2: barrier-free MFMA K-loop, B from global (L2), 4 frags/wave ----
    f32x4 acc0 = (f32x4)0.f, acc1 = (f32x4)0.f, acc2 = (f32x4)0.f, acc3 = (f32x4)0.f;
    const unsigned short* b0p = B0t + (size_t)(wv * 64 +  0 + m15) * 512;
    const unsigned short* b1p = B0t + (size_t)(wv * 64 + 16 + m15) * 512;
    const unsigned short* b2p = B0t + (size_t)(wv * 64 + 32 + m15) * 512;
    const unsigned short* b3p = B0t + (size_t)(wv * 64 + 48 + m15) * 512;
    #pragma unroll
    for (int kt = 0; kt < 16; ++kt) {
        const int kk = kt * 32 + q * 8;
        short8 a  = *reinterpret_cast<const short8*>(&As[m15][kk]);
        short8 b0 = *reinterpret_cast<const short8*>(b0p + kk);
        short8 b1 = *reinterpret_cast<const short8*>(b1p + kk);
        short8 b2 = *reinterpret_cast<const short8*>(b2p + kk);
        short8 b3 = *reinterpret_cast<const short8*>(b3p + kk);
        acc0 = __builtin_amdgcn_mfma_f32_16x16x32_bf16(a, b0, acc0, 0, 0, 0);
        acc1 = __builtin_amdgcn_mfma_f32_16x16x32_bf16(a, b1, acc1, 0, 0, 0);
        acc2 = __builtin_amdgcn_mfma_f32_16x16x32_bf16(a, b2, acc2, 0, 0, 0);
        acc3 = __builtin_amdgcn_mfma_f32_16x16x32_bf16(a, b3, acc3, 0, 0, 0);
    }

    // ---- Epilogue: relu + bf16 write ----
    #pragma unroll
    for (int f = 0; f < 4; ++f) {
        const int n = wv * 64 + f * 16 + m15;
        const f32x4& a = (f == 0) ? acc0 : (f == 1) ? acc1 : (f == 2) ? acc2 : acc3;
        #pragma unroll
        for (int j = 0; j < 4; ++j) {
            int m = r0 + q * 4 + j;
            unsigned short v = f2bf(fmaxf(a[j], 0.f));
            if (isBatch)
                H0[(size_t)m * HIDD + n] = v;
            else
                H1[(size_t)(m - NBATCH) * HIDD + n] = v;
        }
    }
}

// ---------------- kernel 3: layer-1 bf16 MFMA + H1 mean + L2 norm ----------------
// 32 blocks x 512 threads; block = 16 rows x 256 cols. A = [H0 | mean(H1)] bf16
// staged in LDS; B frags from B1t global (L2). Row L2-norm: 16-lane shuffle +
// LDS cross-wave combine. (~8 us, not the bottleneck -- unchanged.)
__global__ __launch_bounds__(512) void k_l1(
    const unsigned short* __restrict__ H0, const unsigned short* __restrict__ H1,
    const unsigned short* __restrict__ B1t, float* __restrict__ out) {
    __shared__ __align__(16) unsigned short As[16][520];
    __shared__ float rn[16][8];
    const int t   = threadIdx.x;
    const int wv  = t >> 6;      // 0..7
    const int l   = t & 63;
    const int q   = l >> 4;
    const int m15 = l & 15;
    const int rb  = blockIdx.x * 16;

    {   // stage H0 half: 512 ushort8 slots, 1/thread
        int r = t >> 5, c8 = (t & 31) * 8;
        *reinterpret_cast<short8*>(&As[r][c8]) =
            *reinterpret_cast<const short8*>(H0 + (size_t)(rb + r) * HIDD + c8);
    }
    {   // stage mean(H1) half: 512 slots, each averages 10 bf16 rows in fp32
        int r = t >> 5, c8 = (t & 31) * 8;
        const unsigned short* base = H1 + (size_t)(rb + r) * FAN1 * HIDD + c8;
        float a[8];
        #pragma unroll
        for (int e = 0; e < 8; ++e) a[e] = 0.f;
        #pragma unroll
        for (int j = 0; j < FAN1; ++j) {
            short8 v = *reinterpret_cast<const short8*>(base + (size_t)j * HIDD);
            #pragma unroll
            for (int e = 0; e < 8; ++e) a[e] += bf2f((unsigned short)v[e]);
        }
        short8 p;
        #pragma unroll
        for (int e = 0; e < 8; ++e) p[e] = (short)f2bf(a[e] * (1.0f / FAN1));
        *reinterpret_cast<short8*>(&As[r][256 + c8]) = p;
    }
    __syncthreads();

    f32x4 acc0 = (f32x4)0.f, acc1 = (f32x4)0.f;
    const unsigned short* b0p = B1t + (size_t)(wv * 32 + m15) * 512;
    const unsigned short* b1p = B1t + (size_t)(wv * 32 + 16 + m15) * 512;
    #pragma unroll
    for (int kt = 0; kt < 8; ++kt) {
        const int kb = kt * 64;
        #pragma unroll
        for (int s2 = 0; s2 < 2; ++s2) {
            const int kk = kb + s2 * 32 + q * 8;
            short8 a  = *reinterpret_cast<const short8*>(&As[m15][kk]);
            short8 b0 = *reinterpret_cast<const short8*>(b0p + kk);
            short8 b1 = *reinterpret_cast<const short8*>(b1p + kk);
            acc0 = __builtin_amdgcn_mfma_f32_16x16x32_bf16(a, b0, acc0, 0, 0, 0);
            acc1 = __builtin_amdgcn_mfma_f32_16x16x32_bf16(a, b1, acc1, 0, 0, 0);
        }
    }

    // per-row sum of squares: reduce over this wave's 16 cols, then cross-wave
    #pragma unroll
    for (int j = 0; j < 4; ++j) {
        float p = acc0[j] * acc0[j] + acc1[j] * acc1[j];
        p += __shfl_xor(p, 1);
        p += __shfl_xor(p, 2);
        p += __shfl_xor(p, 4);
        p += __shfl_xor(p, 8);
        if (m15 == 0) rn[q * 4 + j][wv] = p;
    }
    __syncthreads();

    #pragma unroll
    for (int j = 0; j < 4; ++j) {
        const int m = q * 4 + j;
        float s = rn[m][0] + rn[m][1] + rn[m][2] + rn[m][3]
                + rn[m][4] + rn[m][5] + rn[m][6] + rn[m][7];
        float inv = 1.0f / fmaxf(sqrtf(s), 1e-12f);
        out[(size_t)(rb + m) * HIDD + wv * 32 + m15]      = acc0[j] * inv;
        out[(size_t)(rb + m) * HIDD + wv * 32 + 16 + m15] = acc1[j] * inv;
    }
}

extern "C" void kernel_launch(void* const* d_in, const int* in_sizes, int n_in,
                              void* d_out, int out_size, void* d_ws, size_t ws_size,
                              hipStream_t stream) {
    const float* feat  = (const float*)d_in[0];
    const int*   adj   = (const int*)d_in[1];
    const int*   batch = (const int*)d_in[2];
    const float* Ws0   = (const float*)d_in[3];
    const float* Wn0   = (const float*)d_in[4];
    const float* Ws1   = (const float*)d_in[5];
    const float* Wn1   = (const float*)d_in[6];
    float* out = (float*)d_out;

    // ws: B0t bf16 @0 (262144); B1t bf16 @262144 (262144);
    // H0 bf16 [512][256] @524288 (262144); H1 bf16 [5120][256] @786432 (2621440).
    char* ws = (char*)d_ws;
    unsigned short* B0t = (unsigned short*)(ws + 0);
    unsigned short* B1t = (unsigned short*)(ws + 262144);
    unsigned short* H0  = (unsigned short*)(ws + 524288);
    unsigned short* H1  = (unsigned short*)(ws + 786432);

    k_wcvt<<<64, 256, 0, stream>>>(Ws0, Wn0, Ws1, Wn1, B0t, B1t);
    k_gg0<<<MTOT / 16, 256, 0, stream>>>(feat, adj, batch, B0t, H0, H1);
    k_l1<<<NBATCH / 16, 512, 0, stream>>>(H0, H1, B1t, out);
}

// Round 6
// 192.968 us; speedup vs baseline: 1.3339x; 1.0023x over previous
//
#include <hip/hip_runtime.h>
#include <cstdint>
#include <cstddef>

#define NNODES 100000
#define FEATD  256
#define HIDD   256
#define NBATCH 512
#define FAN1   10            // hop-1 fanout
#define FAN2   25            // hop-2 fanout
#define NS1    (NBATCH*FAN1) // 5120
#define MTOT   (NBATCH+NS1)  // 5632

typedef __attribute__((ext_vector_type(8))) short short8;
typedef __attribute__((ext_vector_type(4))) float f32x4;

__device__ __forceinline__ unsigned short f2bf(float f) {
    unsigned int u = __float_as_uint(f);
    unsigned int r = (u + 0x7fffu + ((u >> 16) & 1u)) >> 16;
    return (unsigned short)r;
}
__device__ __forceinline__ float bf2f(unsigned short h) {
    return __uint_as_float(((unsigned int)h) << 16);
}

// ---------------- kernel 1: W convert+transpose  +  index precompute ----------------
// blocks 0..63  : B0t/B1t[n][k] bf16 (256x512) from Ws/Wn (as before).
// blocks 64..575: b = bid-64. s1[b*10+u] = adj[batch[b]*25+u] (u<10) -- the hop-1
//                 node list, which is ALSO batch row b's neighbor list.
//                 s2[(b*10+u)*25+v] = adj[s1[b*10+u]*25+v] -- hop-2 neighbor lists.
// This pays the 2-deep pointer-chase ONCE with 512-way block parallelism, so the
// gather kernel's per-row address chain drops from depth 3 (batch->adj->adj) to a
// single coalesced index load. (r5 post-mortem: the chase, not load ILP, is the
// gather bottleneck.)
__global__ __launch_bounds__(256) void k_prep(
    const float* __restrict__ Ws0, const float* __restrict__ Wn0,
    const float* __restrict__ Ws1, const float* __restrict__ Wn1,
    const int* __restrict__ adj, const int* __restrict__ batch,
    unsigned short* __restrict__ B0t, unsigned short* __restrict__ B1t,
    int* __restrict__ s1, int* __restrict__ s2) {
    const int t = threadIdx.x;
    if (blockIdx.x < 64) {
        __shared__ unsigned short Ts[64][72];
        const int which = blockIdx.x >> 5;
        const int loc   = blockIdx.x & 31;
        const int kt = loc >> 2, nt = loc & 3;
        const int k0 = kt * 64, n0 = nt * 64;
        const float* W;
        if (which == 0)
            W = (k0 < 256) ? (Ws0 + (size_t)k0 * 256) : (Wn0 + (size_t)(k0 - 256) * 256);
        else
            W = (k0 < 256) ? (Ws1 + (size_t)k0 * 256) : (Wn1 + (size_t)(k0 - 256) * 256);
        unsigned short* Bt = which ? B1t : B0t;
        #pragma unroll
        for (int i = 0; i < 4; ++i) {
            int s  = t + i * 256;
            int kr = s >> 4;
            int c4 = s & 15;
            float4 v = *reinterpret_cast<const float4*>(W + (size_t)kr * 256 + n0 + c4 * 4);
            Ts[c4 * 4 + 0][kr] = f2bf(v.x);
            Ts[c4 * 4 + 1][kr] = f2bf(v.y);
            Ts[c4 * 4 + 2][kr] = f2bf(v.z);
            Ts[c4 * 4 + 3][kr] = f2bf(v.w);
        }
        __syncthreads();
        #pragma unroll
        for (int i = 0; i < 2; ++i) {
            int s  = t + i * 256;
            int nl = s >> 3;
            int k8 = (s & 7) * 8;
            *reinterpret_cast<short8*>(Bt + (size_t)(n0 + nl) * 512 + k0 + k8) =
                *reinterpret_cast<const short8*>(&Ts[nl][k8]);
        }
        return;
    }
    // ---- index build: one block per batch element ----
    __shared__ int hs[FAN1];
    const int b  = blockIdx.x - 64;
    const int nb = batch[b];                       // uniform broadcast load
    if (t < FAN1) {
        int v = adj[(size_t)nb * FAN2 + t];
        s1[b * FAN1 + t] = v;
        hs[t] = v;
    }
    __syncthreads();
    if (t < FAN1 * FAN2) {                         // 250 threads
        const int u = t / FAN2, v = t - u * FAN2;
        s2[(size_t)(b * FAN1 + u) * FAN2 + v] = adj[(size_t)hs[u] * FAN2 + v];
    }
}

// Flat gather over a wave's 4 rows: all index/self loads issued up front
// (depth-1 chains), then one continuous 5-wide/2-deep pipelined neighbor stream
// across row boundaries (no per-row drain bubble). All temp indices compile-time.
template<int FAN>
__device__ __forceinline__ void gather4(
    const float* __restrict__ feat, const int* nidx, const int* node,
    int l, int wv, unsigned short (*As)[520]) {
    static_assert(FAN % 5 == 0, "FAN must be a multiple of 5");
    constexpr int BPR = FAN / 5;     // 5-wide batches per row
    constexpr int NB4 = 4 * BPR;     // batches across the wave's 4 rows
    // self-feature loads: depend only on node[] (already loaded), issue all 4 now
    float4 sv0 = *reinterpret_cast<const float4*>(feat + (size_t)node[0] * FEATD + l * 4);
    float4 sv1 = *reinterpret_cast<const float4*>(feat + (size_t)node[1] * FEATD + l * 4);
    float4 sv2 = *reinterpret_cast<const float4*>(feat + (size_t)node[2] * FEATD + l * 4);
    float4 sv3 = *reinterpret_cast<const float4*>(feat + (size_t)node[3] * FEATD + l * 4);
#define GLD(ROW, K) (*reinterpret_cast<const float4*>( \
        feat + (size_t)__shfl(nidx[ROW], (K)) * FEATD + l * 4))
    float4 c0, c1, c2, c3, c4, n0, n1, n2, n3, n4;
    c0 = GLD(0, 0); c1 = GLD(0, 1); c2 = GLD(0, 2); c3 = GLD(0, 3); c4 = GLD(0, 4);
    float4 a = make_float4(0.f, 0.f, 0.f, 0.f);
    #pragma unroll
    for (int g = 0; g < NB4; ++g) {
        const int row = g / BPR;
        if (g + 1 < NB4) {   // issue next batch (possibly next row) before consuming
            const int nr = (g + 1) / BPR;
            const int nk = ((g + 1) % BPR) * 5;
            n0 = GLD(nr, nk + 0); n1 = GLD(nr, nk + 1); n2 = GLD(nr, nk + 2);
            n3 = GLD(nr, nk + 3); n4 = GLD(nr, nk + 4);
        }
        a.x += (c0.x + c1.x) + (c2.x + c3.x) + c4.x;
        a.y += (c0.y + c1.y) + (c2.y + c3.y) + c4.y;
        a.z += (c0.z + c1.z) + (c2.z + c3.z) + c4.z;
        a.w += (c0.w + c1.w) + (c2.w + c3.w) + c4.w;
        if ((g + 1) % BPR == 0) {    // row complete: finalize in-stream
            const float s = 1.0f / (float)FAN;
            float4 sv = (row == 0) ? sv0 : (row == 1) ? sv1 : (row == 2) ? sv2 : sv3;
            ushort4 ps, pn;
            ps.x = f2bf(sv.x);      ps.y = f2bf(sv.y);
            ps.z = f2bf(sv.z);      ps.w = f2bf(sv.w);
            pn.x = f2bf(a.x * s);   pn.y = f2bf(a.y * s);
            pn.z = f2bf(a.z * s);   pn.w = f2bf(a.w * s);
            const int r = wv * 4 + row;
            *reinterpret_cast<ushort4*>(&As[r][l * 4])       = ps;
            *reinterpret_cast<ushort4*>(&As[r][256 + l * 4]) = pn;
            a = make_float4(0.f, 0.f, 0.f, 0.f);
        }
        if (g + 1 < NB4) { c0 = n0; c1 = n1; c2 = n2; c3 = n3; c4 = n4; }
    }
#undef GLD
}

// ---------------- kernel 2: gather + neighbor-mean + bf16 MFMA GEMM ----------------
// 256 threads = 4 waves; block owns 16 rows x 256 cols. Index lists come
// precomputed (s1/s2) => per-row address chain is ONE coalesced load. adj unused.
__global__ __launch_bounds__(256) void k_gg0(
    const float* __restrict__ feat, const int* __restrict__ batch,
    const int* __restrict__ s1, const int* __restrict__ s2,
    const unsigned short* __restrict__ B0t,
    unsigned short* __restrict__ H0, unsigned short* __restrict__ H1) {
    __shared__ __align__(16) unsigned short As[16][520];
    const int t   = threadIdx.x;
    const int wv  = t >> 6;      // 0..3
    const int l   = t & 63;
    const int q   = l >> 4;
    const int m15 = l & 15;
    const int r0  = blockIdx.x * 16;
    const bool isBatch = (r0 < NBATCH);

    // ---- Phase 1: prefetch all 4 rows' node + index data (independent loads) ----
    int node[4], nidx[4];
    #pragma unroll
    for (int i = 0; i < 4; ++i) {
        const int R = r0 + wv * 4 + i;
        if (isBatch) {
            node[i] = batch[R];                                  // uniform
            nidx[i] = (l < FAN1) ? s1[R * FAN1 + l] : 0;         // coalesced
        } else {
            const int idx = R - NBATCH;
            node[i] = s1[idx];                                   // uniform
            nidx[i] = (l < FAN2) ? s2[(size_t)idx * FAN2 + l] : 0;
        }
    }
    if (isBatch) gather4<FAN1>(feat, nidx, node, l, wv, As);
    else         gather4<FAN2>(feat, nidx, node, l, wv, As);
    __syncthreads();

    // ---- Phase 2: barrier-free MFMA K-loop, B from global (L2), 4 frags/wave ----
    f32x4 acc0 = (f32x4)0.f, acc1 = (f32x4)0.f, acc2 = (f32x4)0.f, acc3 = (f32x4)0.f;
    const unsigned short* b0p = B0t + (size_t)(wv * 64 +  0 + m15) * 512;
    const unsigned short* b1p = B0t + (size_t)(wv * 64 + 16 + m15) * 512;
    const unsigned short* b2p = B0t + (size_t)(wv * 64 + 32 + m15) * 512;
    const unsigned short* b3p = B0t + (size_t)(wv * 64 + 48 + m15) * 512;
    #pragma unroll
    for (int kt = 0; kt < 16; ++kt) {
        const int kk = kt * 32 + q * 8;
        short8 a  = *reinterpret_cast<const short8*>(&As[m15][kk]);
        short8 b0 = *reinterpret_cast<const short8*>(b0p + kk);
        short8 b1 = *reinterpret_cast<const short8*>(b1p + kk);
        short8 b2 = *reinterpret_cast<const short8*>(b2p + kk);
        short8 b3 = *reinterpret_cast<const short8*>(b3p + kk);
        acc0 = __builtin_amdgcn_mfma_f32_16x16x32_bf16(a, b0, acc0, 0, 0, 0);
        acc1 = __builtin_amdgcn_mfma_f32_16x16x32_bf16(a, b1, acc1, 0, 0, 0);
        acc2 = __builtin_amdgcn_mfma_f32_16x16x32_bf16(a, b2, acc2, 0, 0, 0);
        acc3 = __builtin_amdgcn_mfma_f32_16x16x32_bf16(a, b3, acc3, 0, 0, 0);
    }

    // ---- Epilogue: relu + bf16 write ----
    #pragma unroll
    for (int f = 0; f < 4; ++f) {
        const int n = wv * 64 + f * 16 + m15;
        const f32x4& a = (f == 0) ? acc0 : (f == 1) ? acc1 : (f == 2) ? acc2 : acc3;
        #pragma unroll
        for (int j = 0; j < 4; ++j) {
            int m = r0 + q * 4 + j;
            unsigned short v = f2bf(fmaxf(a[j], 0.f));
            if (isBatch)
                H0[(size_t)m * HIDD + n] = v;
            else
                H1[(size_t)(m - NBATCH) * HIDD + n] = v;
        }
    }
}

// ---------------- kernel 3: layer-1 bf16 MFMA + H1 mean + L2 norm ----------------
// 32 blocks x 512 threads; block = 16 rows x 256 cols. A = [H0 | mean(H1)] bf16
// staged in LDS; B frags from B1t global (L2). Unchanged.
__global__ __launch_bounds__(512) void k_l1(
    const unsigned short* __restrict__ H0, const unsigned short* __restrict__ H1,
    const unsigned short* __restrict__ B1t, float* __restrict__ out) {
    __shared__ __align__(16) unsigned short As[16][520];
    __shared__ float rn[16][8];
    const int t   = threadIdx.x;
    const int wv  = t >> 6;      // 0..7
    const int l   = t & 63;
    const int q   = l >> 4;
    const int m15 = l & 15;
    const int rb  = blockIdx.x * 16;

    {   // stage H0 half: 512 ushort8 slots, 1/thread
        int r = t >> 5, c8 = (t & 31) * 8;
        *reinterpret_cast<short8*>(&As[r][c8]) =
            *reinterpret_cast<const short8*>(H0 + (size_t)(rb + r) * HIDD + c8);
    }
    {   // stage mean(H1) half: 512 slots, each averages 10 bf16 rows in fp32
        int r = t >> 5, c8 = (t & 31) * 8;
        const unsigned short* base = H1 + (size_t)(rb + r) * FAN1 * HIDD + c8;
        float a[8];
        #pragma unroll
        for (int e = 0; e < 8; ++e) a[e] = 0.f;
        #pragma unroll
        for (int j = 0; j < FAN1; ++j) {
            short8 v = *reinterpret_cast<const short8*>(base + (size_t)j * HIDD);
            #pragma unroll
            for (int e = 0; e < 8; ++e) a[e] += bf2f((unsigned short)v[e]);
        }
        short8 p;
        #pragma unroll
        for (int e = 0; e < 8; ++e) p[e] = (short)f2bf(a[e] * (1.0f / FAN1));
        *reinterpret_cast<short8*>(&As[r][256 + c8]) = p;
    }
    __syncthreads();

    f32x4 acc0 = (f32x4)0.f, acc1 = (f32x4)0.f;
    const unsigned short* b0p = B1t + (size_t)(wv * 32 + m15) * 512;
    const unsigned short* b1p = B1t + (size_t)(wv * 32 + 16 + m15) * 512;
    #pragma unroll
    for (int kt = 0; kt < 8; ++kt) {
        const int kb = kt * 64;
        #pragma unroll
        for (int s2i = 0; s2i < 2; ++s2i) {
            const int kk = kb + s2i * 32 + q * 8;
            short8 a  = *reinterpret_cast<const short8*>(&As[m15][kk]);
            short8 b0 = *reinterpret_cast<const short8*>(b0p + kk);
            short8 b1 = *reinterpret_cast<const short8*>(b1p + kk);
            acc0 = __builtin_amdgcn_mfma_f32_16x16x32_bf16(a, b0, acc0, 0, 0, 0);
            acc1 = __builtin_amdgcn_mfma_f32_16x16x32_bf16(a, b1, acc1, 0, 0, 0);
        }
    }

    // per-row sum of squares: reduce over this wave's 16 cols, then cross-wave
    #pragma unroll
    for (int j = 0; j < 4; ++j) {
        float p = acc0[j] * acc0[j] + acc1[j] * acc1[j];
        p += __shfl_xor(p, 1);
        p += __shfl_xor(p, 2);
        p += __shfl_xor(p, 4);
        p += __shfl_xor(p, 8);
        if (m15 == 0) rn[q * 4 + j][wv] = p;
    }
    __syncthreads();

    #pragma unroll
    for (int j = 0; j < 4; ++j) {
        const int m = q * 4 + j;
        float s = rn[m][0] + rn[m][1] + rn[m][2] + rn[m][3]
                + rn[m][4] + rn[m][5] + rn[m][6] + rn[m][7];
        float inv = 1.0f / fmaxf(sqrtf(s), 1e-12f);
        out[(size_t)(rb + m) * HIDD + wv * 32 + m15]      = acc0[j] * inv;
        out[(size_t)(rb + m) * HIDD + wv * 32 + 16 + m15] = acc1[j] * inv;
    }
}

extern "C" void kernel_launch(void* const* d_in, const int* in_sizes, int n_in,
                              void* d_out, int out_size, void* d_ws, size_t ws_size,
                              hipStream_t stream) {
    const float* feat  = (const float*)d_in[0];
    const int*   adj   = (const int*)d_in[1];
    const int*   batch = (const int*)d_in[2];
    const float* Ws0   = (const float*)d_in[3];
    const float* Wn0   = (const float*)d_in[4];
    const float* Ws1   = (const float*)d_in[5];
    const float* Wn1   = (const float*)d_in[6];
    float* out = (float*)d_out;

    // ws: B0t bf16 @0 (262144); B1t bf16 @262144 (262144);
    // H0 bf16 [512][256] @524288 (262144); H1 bf16 [5120][256] @786432 (2621440);
    // s1 int[5120] @3407872 (20480); s2 int[128000] @3428352 (512000).
    char* ws = (char*)d_ws;
    unsigned short* B0t = (unsigned short*)(ws + 0);
    unsigned short* B1t = (unsigned short*)(ws + 262144);
    unsigned short* H0  = (unsigned short*)(ws + 524288);
    unsigned short* H1  = (unsigned short*)(ws + 786432);
    int*            s1  = (int*)(ws + 3407872);
    int*            s2  = (int*)(ws + 3428352);

    k_prep<<<64 + NBATCH, 256, 0, stream>>>(Ws0, Wn0, Ws1, Wn1, adj, batch,
                                            B0t, B1t, s1, s2);
    k_gg0<<<MTOT / 16, 256, 0, stream>>>(feat, batch, s1, s2, B0t, H0, H1);
    k_l1<<<NBATCH / 16, 512, 0, stream>>>(H0, H1, B1t, out);
}